// Round 9
// baseline (2322.112 us; speedup 1.0000x reference)
//
#include <hip/hip_runtime.h>
#include <hip/hip_fp16.h>

// Bidirectional GRU (B=64,S=1024,E=H=256) + FC/ReLU head — chunked pipeline.
// k_gx: gx = x@W_ih^T (+biases), f16 MFMA; PRE-SCALED by -log2e (r,z) / +2log2e (n);
//       consumer layout [dir][t][bsl][tid512][3 gates][8] -> one base, imm offsets.
// k_rec: persistent 8 WGs (2dir x 4bslice) x 512 thr, launch_bounds(512,2).
//        Register-frugal (peak live < 256 unified). Step reordered to hide the
//        gate tail: MFMA{r0,r1,z0,z1} -> r/z gates (both jt, overlap group B)
//        -> MFMA{n0,n1} -> n-gate + h tail only -> lgkm-only barrier.
//        h in LDS in MFMA-A-frag order (linear conflict-free ds_read_b128),
//        ping-pong tiles, raw s_barrier, immediate out stores.
// k_fc: relu(concat @ W_fc^T + b) in place over f16 h written into d_out.

typedef _Float16 f16x8 __attribute__((ext_vector_type(8)));
typedef _Float16 f16x4 __attribute__((ext_vector_type(4)));
typedef float    f32x4 __attribute__((ext_vector_type(4)));

#define MFMA(a,b,c) __builtin_amdgcn_mfma_f32_16x16x32_f16((a),(b),(c),0,0,0)
#define SWZ(r,c)  ((((r)*512)  + (c)) ^ (((r)&7)<<4))
#define SWZ2(r,c) ((((r)*1024) + (c)) ^ (((r)&7)<<4))

#define NLOG2E (-1.442695041f)
#define P2LOG2E (2.885390082f)

__device__ inline f16x8 pack8(float4 a, float4 b){
  f16x8 h;
  h[0]=(_Float16)a.x; h[1]=(_Float16)a.y; h[2]=(_Float16)a.z; h[3]=(_Float16)a.w;
  h[4]=(_Float16)b.x; h[5]=(_Float16)b.y; h[6]=(_Float16)b.z; h[7]=(_Float16)b.w;
  return h;
}
__device__ inline f16x8 pack8s(float4 a, float4 b, float s){
  f16x8 h;
  h[0]=(_Float16)(a.x*s); h[1]=(_Float16)(a.y*s); h[2]=(_Float16)(a.z*s); h[3]=(_Float16)(a.w*s);
  h[4]=(_Float16)(b.x*s); h[5]=(_Float16)(b.y*s); h[6]=(_Float16)(b.z*s); h[7]=(_Float16)(b.w*s);
  return h;
}

// ---------------- gx: gx = scale * (x @ W_ih^T + b_ih (+ b_hh for r,z)) ----------------
__global__ __launch_bounds__(256) void k_gx(
    const float* __restrict__ X,
    const float* __restrict__ Wf, const float* __restrict__ bihf, const float* __restrict__ bhhf,
    const float* __restrict__ Wb, const float* __restrict__ bihb, const float* __restrict__ bhhb,
    _Float16* __restrict__ gxc, int CT, int sbase)
{
  const int tc = blockIdx.x, dir = blockIdx.y;
  const int p = sbase + tc;
  const int t = dir ? (1023 - p) : p;
  const float* __restrict__ Wp = dir ? Wb : Wf;
  const float* __restrict__ bi = dir ? bihb : bihf;
  const float* __restrict__ bh = dir ? bhhb : bhhf;
  __shared__ _Float16 As[64*256];            // 32KB
  __shared__ _Float16 Bs[64*256];            // 32KB
  const int tid = threadIdx.x;
  #pragma unroll
  for (int i = 0; i < 8; ++i) {              // stage A: rows = batch b, fixed t
    int c = tid + i*256, r = c >> 5, cc = c & 31;
    const float4* s4 = (const float4*)(X + ((size_t)r*1024 + t)*256 + cc*8);
    *(f16x8*)((char*)As + SWZ(r, cc*16)) = pack8(s4[0], s4[1]);
  }
  const int w = tid >> 6, l = tid & 63, lr = l & 15, g = l >> 4;
  const size_t obase = (((size_t)dir*CT + tc)*4 + w) * (size_t)12288;  // f16 units
  #pragma unroll 1
  for (int nt = 0; nt < 12; ++nt) {
    __syncthreads();
    #pragma unroll
    for (int i = 0; i < 8; ++i) {            // stage B: W rows nt*64..+64
      int c = tid + i*256, r = c >> 5, cc = c & 31;
      const float4* s4 = (const float4*)(Wp + (size_t)(nt*64 + r)*256 + cc*8);
      *(f16x8*)((char*)Bs + SWZ(r, cc*16)) = pack8(s4[0], s4[1]);
    }
    __syncthreads();
    f32x4 acc[4];
    #pragma unroll
    for (int ct = 0; ct < 4; ++ct) acc[ct] = (f32x4){0.f,0.f,0.f,0.f};
    #pragma unroll
    for (int kk = 0; kk < 8; ++kk) {
      f16x8 af = *(const f16x8*)((const char*)As + SWZ(w*16 + lr, kk*64 + g*16));
      #pragma unroll
      for (int ct = 0; ct < 4; ++ct) {
        f16x8 bfr = *(const f16x8*)((const char*)Bs + SWZ(ct*16 + lr, kk*64 + g*16));
        acc[ct] = MFMA(af, bfr, acc[ct]);
      }
    }
    #pragma unroll
    for (int ct = 0; ct < 4; ++ct) {         // consumer layout [tid512][3][8]
      const int col = nt*64 + ct*16 + lr;
      const int gate = col >> 8;
      const float sc = (gate == 2) ? P2LOG2E : NLOG2E;
      const float bv = bi[col] + (gate < 2 ? bh[col] : 0.f);
      const int j = col & 255;
      const int tid2 = (j>>5)*64 + g*16 + (j&15);
      const int off = ((j>>4)&1)*4;          // jt*4
      f16x4 v;
      #pragma unroll
      for (int q = 0; q < 4; ++q) v[q] = (_Float16)((acc[ct][q] + bv)*sc);
      *(f16x4*)(gxc + obase + (size_t)tid2*24 + gate*8 + off) = v;
    }
  }
}

// ---------------- GRU recurrence, one chunk of CT steps ----------------
// h tile in A-frag order: h[r][k] at byte (k>>5)*1024 + ((k>>3)&3)*256 + r*16 + (k&7)*2;
// af read for kk = ds_read_b128 at l*16 + kk*1024 (linear, conflict-free).
// Thread (w,l) produces h[g*4+q][w*32+jt*16+lr].
// Gates (pre-scaled): r = rcp(1+exp2(xr'+hr')), z likewise,
//                     n = 1 - 2*rcp(1+exp2(xn' + r*hn')), h = n + z*(h_old-n).
__global__ __launch_bounds__(512, 2) void k_rec(
    const float* __restrict__ Whh_f, const float* __restrict__ bhh_f,
    const float* __restrict__ Whh_b, const float* __restrict__ bhh_b,
    const _Float16* __restrict__ gxc, float* __restrict__ wsh,
    _Float16* __restrict__ out16, float* __restrict__ hidden,
    int CT, int sbase)
{
  const int dir = blockIdx.x & 1;
  const int bsl = blockIdx.x >> 1;
  const int bbase = bsl * 16;
  const float* __restrict__ Whh = dir ? Whh_b : Whh_f;
  const float* __restrict__ bhh = dir ? bhh_b : bhh_f;
  const int tid = threadIdx.x, w = tid >> 6, l = tid & 63;
  const int lr = l & 15, g = l >> 4;
  const int j0 = w * 32;
  f16x8 wf[6][8];                            // B-frag: W[col][k=kk*32+g*8+i], pre-scaled
  #pragma unroll
  for (int ct = 0; ct < 6; ++ct) {
    const int colg = (ct>>1)*256 + j0 + (ct&1)*16 + lr;
    const float scl = (ct < 4) ? NLOG2E : P2LOG2E;
    #pragma unroll
    for (int kk = 0; kk < 8; ++kk) {
      const float4* s4 = (const float4*)(Whh + (size_t)colg*256 + kk*32 + g*8);
      wf[ct][kk] = pack8s(s4[0], s4[1], scl);
    }
  }
  const float bn0 = P2LOG2E * bhh[512 + j0 + lr];        // n-gate bhh, pre-scaled
  const float bn1 = P2LOG2E * bhh[512 + j0 + 16 + lr];
  __shared__ _Float16 hs[2][4096];           // ping-pong A-frag-ordered h tiles (16KB)
  char* const afp = (char*)hs + l*16;
  char* const hwp = (char*)hs + w*1024 + (lr>>3)*256 + g*64 + (lr&7)*2;
  float hold[2][4];
  if (sbase == 0) {
    *(int4*)((char*)hs + tid*16) = make_int4(0,0,0,0);   // hs[0] := 0 (8KB exact)
    #pragma unroll
    for (int jt = 0; jt < 2; ++jt)
      #pragma unroll
      for (int q = 0; q < 4; ++q) hold[jt][q] = 0.f;
  } else {                                   // restore h from previous chunk
    const int r = tid >> 5, kq = tid & 31;
    const float4* s4 = (const float4*)(wsh + ((size_t)(dir*64 + bbase + r))*256 + kq*8);
    *(f16x8*)((char*)hs + (kq>>2)*1024 + (((kq&3)*16) + r)*16) = pack8(s4[0], s4[1]);
    #pragma unroll
    for (int jt = 0; jt < 2; ++jt)
      #pragma unroll
      for (int q = 0; q < 4; ++q)
        hold[jt][q] = wsh[((size_t)(dir*64 + bbase + g*4 + q))*256 + j0 + jt*16 + lr];
  }
  __syncthreads();

  const int t0 = dir ? (1023 - sbase) : sbase;
  char* optr = (char*)out16 + ((size_t)t0*64 + bbase + g*4)*1024
             + (size_t)(dir*256 + j0 + lr)*2;
  const ptrdiff_t ostep = dir ? -(ptrdiff_t)65536 : (ptrdiff_t)65536;
  const _Float16* gp = gxc + ((size_t)(dir*CT)*4 + bsl)*12288 + (size_t)tid*24;
  const ptrdiff_t gstep = 4*12288;

// One step: gx loads -> MFMA group A {r0,r1,z0,z1} -> r/z gates (both jt;
// overlappable with group B) -> MFMA group B {n0,n1} -> n-gate + h tail ->
// LDS h write + out store -> lgkm-only barrier.
#define REC_STEP(RB)                                                               \
  {                                                                                \
    const f16x8 gv0 = *(const f16x8*)(gp);                                         \
    const f16x8 gv1 = *(const f16x8*)(gp + 8);                                     \
    const f16x8 gv2 = *(const f16x8*)(gp + 16);                                    \
    gp += gstep;                                                                   \
    f32x4 rv0, rv1, zv0, zv1;                                                      \
    {                                                                              \
      f32x4 ar0 = (f32x4){0.f,0.f,0.f,0.f};                                        \
      f32x4 ar1 = (f32x4){0.f,0.f,0.f,0.f};                                        \
      f32x4 az0 = (f32x4){0.f,0.f,0.f,0.f};                                        \
      f32x4 az1 = (f32x4){0.f,0.f,0.f,0.f};                                        \
      _Pragma("unroll")                                                            \
      for (int kk = 0; kk < 8; ++kk) {                                             \
        const f16x8 af = *(const f16x8*)(afp + (RB)*8192 + kk*1024);               \
        ar0 = MFMA(af, wf[0][kk], ar0);                                            \
        ar1 = MFMA(af, wf[1][kk], ar1);                                            \
        az0 = MFMA(af, wf[2][kk], az0);                                            \
        az1 = MFMA(af, wf[3][kk], az1);                                            \
      }                                                                            \
      _Pragma("unroll")                                                            \
      for (int q = 0; q < 4; ++q) {                                                \
        rv0[q] = __builtin_amdgcn_rcpf(                                            \
            1.f + __builtin_amdgcn_exp2f((float)gv0[q] + ar0[q]));                 \
        rv1[q] = __builtin_amdgcn_rcpf(                                            \
            1.f + __builtin_amdgcn_exp2f((float)gv0[4+q] + ar1[q]));               \
        zv0[q] = __builtin_amdgcn_rcpf(                                            \
            1.f + __builtin_amdgcn_exp2f((float)gv1[q] + az0[q]));                 \
        zv1[q] = __builtin_amdgcn_rcpf(                                            \
            1.f + __builtin_amdgcn_exp2f((float)gv1[4+q] + az1[q]));               \
      }                                                                            \
    }                                                                              \
    {                                                                              \
      f32x4 an0 = (f32x4){bn0,bn0,bn0,bn0};                                        \
      f32x4 an1 = (f32x4){bn1,bn1,bn1,bn1};                                        \
      _Pragma("unroll")                                                            \
      for (int kk = 0; kk < 8; ++kk) {                                             \
        const f16x8 af = *(const f16x8*)(afp + (RB)*8192 + kk*1024);               \
        an0 = MFMA(af, wf[4][kk], an0);                                            \
        an1 = MFMA(af, wf[5][kk], an1);                                            \
      }                                                                            \
      _Pragma("unroll")                                                            \
      for (int q = 0; q < 4; ++q) {                                                \
        const float nv0 = __builtin_fmaf(-2.f, __builtin_amdgcn_rcpf(              \
            1.f + __builtin_amdgcn_exp2f(                                          \
                __builtin_fmaf(rv0[q], an0[q], (float)gv2[q]))), 1.f);             \
        const float h0 = __builtin_fmaf(zv0[q], hold[0][q] - nv0, nv0);            \
        hold[0][q] = h0;                                                           \
        const _Float16 hf0 = (_Float16)h0;                                         \
        *(_Float16*)(hwp + ((RB)^1)*8192 + q*16) = hf0;                            \
        *(_Float16*)(optr + q*1024) = hf0;                                         \
        const float nv1 = __builtin_fmaf(-2.f, __builtin_amdgcn_rcpf(              \
            1.f + __builtin_amdgcn_exp2f(                                          \
                __builtin_fmaf(rv1[q], an1[q], (float)gv2[4+q]))), 1.f);           \
        const float h1 = __builtin_fmaf(zv1[q], hold[1][q] - nv1, nv1);            \
        hold[1][q] = h1;                                                           \
        const _Float16 hf1 = (_Float16)h1;                                         \
        *(_Float16*)(hwp + ((RB)^1)*8192 + 512 + q*16) = hf1;                      \
        *(_Float16*)(optr + q*1024 + 32) = hf1;                                    \
      }                                                                            \
    }                                                                              \
    optr += ostep;                                                                 \
    asm volatile("s_waitcnt lgkmcnt(0)" ::: "memory");                             \
    __builtin_amdgcn_s_barrier();                                                  \
    asm volatile("" ::: "memory");                                                 \
  }

  #pragma unroll 1
  for (int sc = 0; sc < CT; sc += 2) {
    REC_STEP(0)
    REC_STEP(1)
  }
#undef REC_STEP

  if (sbase + CT == 1024) {                  // final h -> hidden output
    #pragma unroll
    for (int jt = 0; jt < 2; ++jt)
      #pragma unroll
      for (int q = 0; q < 4; ++q)
        hidden[((size_t)(dir*64 + bbase + g*4 + q))*256 + j0 + jt*16 + lr] = hold[jt][q];
  } else {                                   // persist h for next chunk
    #pragma unroll
    for (int jt = 0; jt < 2; ++jt)
      #pragma unroll
      for (int q = 0; q < 4; ++q)
        wsh[((size_t)(dir*64 + bbase + g*4 + q))*256 + j0 + jt*16 + lr] = hold[jt][q];
  }
}

// ---------------- FC in place: relu(concat_f16 @ W_fc^T + b) -> f32 ----------------
__global__ __launch_bounds__(256) void k_fc(
    const _Float16* __restrict__ h16, const float* __restrict__ Wfc,
    const float* __restrict__ bfc, float* __restrict__ out)
{
  const int mt = blockIdx.x;
  __shared__ _Float16 As[64*512];            // 64KB
  const int tid = threadIdx.x, w = tid >> 6, l = tid & 63;
  const int lr = l & 15, g = l >> 4;
  #pragma unroll
  for (int i = 0; i < 16; ++i) {
    int c = tid + i*256, r = c >> 6, cc = c & 63;
    *(int4*)((char*)As + SWZ2(r, cc*16)) =
        *(const int4*)((const char*)h16 + ((size_t)mt*64 + r)*1024 + cc*16);
  }
  __syncthreads();                           // all h16 reads drained before any store
  #pragma unroll 1
  for (int nt = 0; nt < 4; ++nt) {
    f32x4 acc[4];
    #pragma unroll
    for (int ct = 0; ct < 4; ++ct) acc[ct] = (f32x4){0.f,0.f,0.f,0.f};
    #pragma unroll 2
    for (int kk = 0; kk < 16; ++kk) {
      f16x8 af = *(const f16x8*)((const char*)As + SWZ2(w*16 + lr, kk*64 + g*16));
      #pragma unroll
      for (int ct = 0; ct < 4; ++ct) {
        const float4* s4 = (const float4*)(Wfc + (size_t)(nt*64 + ct*16 + lr)*512 + kk*32 + g*8);
        acc[ct] = MFMA(af, pack8(s4[0], s4[1]), acc[ct]);
      }
    }
    #pragma unroll
    for (int ct = 0; ct < 4; ++ct) {
      const int col = nt*64 + ct*16 + lr;
      const float bv = bfc[col];
      #pragma unroll
      for (int q = 0; q < 4; ++q) {
        const int row = w*16 + g*4 + q;
        out[((size_t)mt*64 + row)*256 + col] = fmaxf(acc[ct][q] + bv, 0.f);
      }
    }
  }
}

extern "C" void kernel_launch(void* const* d_in, const int* in_sizes, int n_in,
                              void* d_out, int out_size, void* d_ws, size_t ws_size,
                              hipStream_t stream) {
  const float* X      = (const float*)d_in[0];
  const float* W_ih_f = (const float*)d_in[1];
  const float* W_hh_f = (const float*)d_in[2];
  const float* b_ih_f = (const float*)d_in[3];
  const float* b_hh_f = (const float*)d_in[4];
  const float* W_ih_b = (const float*)d_in[5];
  const float* W_hh_b = (const float*)d_in[6];
  const float* b_ih_b = (const float*)d_in[7];
  const float* b_hh_b = (const float*)d_in[8];
  const float* W_fc   = (const float*)d_in[9];
  const float* b_fc   = (const float*)d_in[10];

  // CT=256 keeps the gxc chunk (50MB) L3-resident.
  int CT = 256;
  while (CT > 8 && ((size_t)CT*196608 + 131072) > ws_size) CT >>= 1;
  _Float16* gxc = (_Float16*)d_ws;                     // [2][CT][4][512][3][8] f16
  float*    wsh = (float*)((char*)d_ws + (size_t)CT*196608);  // [2][64][256] f32

  _Float16* h16   = (_Float16*)d_out;                  // [1024][64][512] f16 (in-place)
  float*    out   = (float*)d_out;                     // [1024][64][256] f32
  float*    hidden= (float*)d_out + (size_t)1024*64*256;

  const int NC = 1024 / CT;
  for (int c = 0; c < NC; ++c) {
    k_gx<<<dim3(CT, 2), dim3(256), 0, stream>>>(X, W_ih_f, b_ih_f, b_hh_f,
                                                W_ih_b, b_ih_b, b_hh_b, gxc, CT, c*CT);
    k_rec<<<dim3(8), dim3(512), 0, stream>>>(W_hh_f, b_hh_f, W_hh_b, b_hh_b,
                                             gxc, wsh, h16, hidden, CT, c*CT);
  }
  k_fc<<<dim3(1024), dim3(256), 0, stream>>>(h16, W_fc, b_fc, out);
}

// Round 10
// 2105.211 us; speedup vs baseline: 1.1030x; 1.1030x over previous
//
#include <hip/hip_runtime.h>
#include <hip/hip_fp16.h>

// Bidirectional GRU (B=64,S=1024,E=H=256) + FC/ReLU head.
// k_gx0: gx chunk 0 (prologue). k_step: blocks 0-7 = GRU recurrence on chunk c
//        (8 CUs), blocks 8.. = gx for chunk c+1 on the other ~248 CUs (hidden
//        under the recurrence; gxc double-buffered, dependency via kernel
//        boundary). k_fc: relu(concat @ W_fc^T + b) in place.
// Recurrence: 512 thr, launch_bounds(512,2), W_hh f16 frags reg-resident
// (pre-scaled -log2e / 2log2e for exp2 gates), h in LDS in MFMA-A-frag order,
// ping-pong tiles, one lgkm-only raw barrier per step, wave-parity setprio(1)
// to skew odd waves ahead (their gate VALU overlaps even waves' MFMA issue).

typedef _Float16 f16x8 __attribute__((ext_vector_type(8)));
typedef _Float16 f16x4 __attribute__((ext_vector_type(4)));
typedef float    f32x4 __attribute__((ext_vector_type(4)));

#define MFMA(a,b,c) __builtin_amdgcn_mfma_f32_16x16x32_f16((a),(b),(c),0,0,0)
#define SWZ(r,c)  ((((r)*512)  + (c)) ^ (((r)&7)<<4))
#define SWZ2(r,c) ((((r)*1024) + (c)) ^ (((r)&7)<<4))

#define NLOG2E (-1.442695041f)
#define P2LOG2E (2.885390082f)

__device__ inline f16x8 pack8(float4 a, float4 b){
  f16x8 h;
  h[0]=(_Float16)a.x; h[1]=(_Float16)a.y; h[2]=(_Float16)a.z; h[3]=(_Float16)a.w;
  h[4]=(_Float16)b.x; h[5]=(_Float16)b.y; h[6]=(_Float16)b.z; h[7]=(_Float16)b.w;
  return h;
}
__device__ inline f16x8 pack8s(float4 a, float4 b, float s){
  f16x8 h;
  h[0]=(_Float16)(a.x*s); h[1]=(_Float16)(a.y*s); h[2]=(_Float16)(a.z*s); h[3]=(_Float16)(a.w*s);
  h[4]=(_Float16)(b.x*s); h[5]=(_Float16)(b.y*s); h[6]=(_Float16)(b.z*s); h[7]=(_Float16)(b.w*s);
  return h;
}

// ---------------- gx body: 512 threads, one (t,dir); waves 4-7 stage-only ----------------
__device__ __forceinline__ void gx_body(
    char* smem, const float* __restrict__ X,
    const float* __restrict__ Wp, const float* __restrict__ bi, const float* __restrict__ bh,
    _Float16* __restrict__ gxc, int CT, int tc, int dir, int t)
{
  _Float16* As = (_Float16*)smem;            // 32KB
  _Float16* Bs = (_Float16*)(smem + 32768);  // 32KB
  const int tid = threadIdx.x;
  #pragma unroll
  for (int i = 0; i < 4; ++i) {              // stage A: rows = batch b, fixed t
    int c = tid + i*512, r = c >> 5, cc = c & 31;
    const float4* s4 = (const float4*)(X + ((size_t)r*1024 + t)*256 + cc*8);
    *(f16x8*)((char*)As + SWZ(r, cc*16)) = pack8(s4[0], s4[1]);
  }
  const int w = tid >> 6, l = tid & 63, lr = l & 15, g = l >> 4;
  const size_t obase = (((size_t)dir*CT + tc)*4 + (w & 3)) * (size_t)12288;
  #pragma unroll 1
  for (int nt = 0; nt < 12; ++nt) {
    __syncthreads();
    #pragma unroll
    for (int i = 0; i < 4; ++i) {            // stage B: W rows nt*64..+64
      int c = tid + i*512, r = c >> 5, cc = c & 31;
      const float4* s4 = (const float4*)(Wp + (size_t)(nt*64 + r)*256 + cc*8);
      *(f16x8*)((char*)Bs + SWZ(r, cc*16)) = pack8(s4[0], s4[1]);
    }
    __syncthreads();
    if (w < 4) {                             // waves 0-3 compute; 4-7 idle at barriers
      f32x4 acc[4];
      #pragma unroll
      for (int ct = 0; ct < 4; ++ct) acc[ct] = (f32x4){0.f,0.f,0.f,0.f};
      #pragma unroll
      for (int kk = 0; kk < 8; ++kk) {
        f16x8 af = *(const f16x8*)((const char*)As + SWZ(w*16 + lr, kk*64 + g*16));
        #pragma unroll
        for (int ct = 0; ct < 4; ++ct) {
          f16x8 bfr = *(const f16x8*)((const char*)Bs + SWZ(ct*16 + lr, kk*64 + g*16));
          acc[ct] = MFMA(af, bfr, acc[ct]);
        }
      }
      #pragma unroll
      for (int ct = 0; ct < 4; ++ct) {       // consumer layout [tid512][3][8]
        const int col = nt*64 + ct*16 + lr;
        const int gate = col >> 8;
        const float sc = (gate == 2) ? P2LOG2E : NLOG2E;
        const float bv = bi[col] + (gate < 2 ? bh[col] : 0.f);
        const int j = col & 255;
        const int tid2 = (j>>5)*64 + g*16 + (j&15);
        const int off = ((j>>4)&1)*4;        // jt*4
        f16x4 v;
        #pragma unroll
        for (int q = 0; q < 4; ++q) v[q] = (_Float16)((acc[ct][q] + bv)*sc);
        *(f16x4*)(gxc + obase + (size_t)tid2*24 + gate*8 + off) = v;
      }
    }
  }
}

// ---------------- gx prologue kernel (chunk 0) ----------------
__global__ __launch_bounds__(512, 2) void k_gx0(
    const float* __restrict__ X,
    const float* __restrict__ Wf, const float* __restrict__ bihf, const float* __restrict__ bhhf,
    const float* __restrict__ Wb, const float* __restrict__ bihb, const float* __restrict__ bhhb,
    _Float16* __restrict__ gxc, int CT, int sbase)
{
  __shared__ char smem[65536];
  const int tc = blockIdx.x, dir = blockIdx.y;
  const int p = sbase + tc;
  const int t = dir ? (1023 - p) : p;
  gx_body(smem, X, dir ? Wb : Wf, dir ? bihb : bihf, dir ? bhhb : bhhf,
          gxc, CT, tc, dir, t);
}

// ---------------- merged step: rec(chunk c) + gx(chunk c+1) ----------------
// rec h tile in A-frag order: h[r][k] at byte (k>>5)*1024+((k>>3)&3)*256+r*16+(k&7)*2;
// af read for kk = ds_read_b128 at l*16 + kk*1024 (linear, conflict-free).
// Thread (w,l) produces h[g*4+q][w*32+jt*16+lr].
__global__ __launch_bounds__(512, 2) void k_step(
    const float* __restrict__ Whh_f, const float* __restrict__ bhh_f,
    const float* __restrict__ Whh_b, const float* __restrict__ bhh_b,
    const _Float16* __restrict__ gxin, float* __restrict__ wsh,
    _Float16* __restrict__ out16, float* __restrict__ hidden,
    int CT, int sbase,
    const float* __restrict__ X,
    const float* __restrict__ Wf, const float* __restrict__ bihf, const float* __restrict__ bhhf,
    const float* __restrict__ Wb, const float* __restrict__ bihb, const float* __restrict__ bhhb,
    _Float16* __restrict__ gxout, int sbase_gx, int gx_valid)
{
  __shared__ char smem[65536];
  if (blockIdx.x >= 8) {                     // ---- gx role: chunk c+1 ----
    if (!gx_valid) return;
    const int b = blockIdx.x - 8;
    const int tc = b >> 1, dir = b & 1;
    const int p = sbase_gx + tc;
    const int t = dir ? (1023 - p) : p;
    gx_body(smem, X, dir ? Wb : Wf, dir ? bihb : bihf, dir ? bhhb : bhhf,
            gxout, CT, tc, dir, t);
    return;
  }
  // ---- recurrence role (blocks 0-7) ----
  const int dir = blockIdx.x & 1;
  const int bsl = blockIdx.x >> 1;
  const int bbase = bsl * 16;
  const float* __restrict__ Whh = dir ? Whh_b : Whh_f;
  const float* __restrict__ bhh = dir ? bhh_b : bhh_f;
  const int tid = threadIdx.x, w = tid >> 6, l = tid & 63;
  const int lr = l & 15, g = l >> 4;
  const int j0 = w * 32;
  f16x8 wf[6][8];                            // B-frag: W[col][k=kk*32+g*8+i], pre-scaled
  #pragma unroll
  for (int ct = 0; ct < 6; ++ct) {
    const int colg = (ct>>1)*256 + j0 + (ct&1)*16 + lr;
    const float scl = (ct < 4) ? NLOG2E : P2LOG2E;
    #pragma unroll
    for (int kk = 0; kk < 8; ++kk) {
      const float4* s4 = (const float4*)(Whh + (size_t)colg*256 + kk*32 + g*8);
      wf[ct][kk] = pack8s(s4[0], s4[1], scl);
    }
  }
  const float bn0 = P2LOG2E * bhh[512 + j0 + lr];        // n-gate bhh, pre-scaled
  const float bn1 = P2LOG2E * bhh[512 + j0 + 16 + lr];
  char* const hsb = smem;                    // ping-pong A-frag h tiles (16KB used)
  char* const afp = hsb + l*16;
  char* const hwp = hsb + w*1024 + (lr>>3)*256 + g*64 + (lr&7)*2;
  float hold[2][4];
  if (sbase == 0) {
    *(int4*)(hsb + tid*16) = make_int4(0,0,0,0);         // hs[0] := 0 (8KB exact)
    #pragma unroll
    for (int jt = 0; jt < 2; ++jt)
      #pragma unroll
      for (int q = 0; q < 4; ++q) hold[jt][q] = 0.f;
  } else {                                   // restore h from previous chunk
    const int r = tid >> 5, kq = tid & 31;
    const float4* s4 = (const float4*)(wsh + ((size_t)(dir*64 + bbase + r))*256 + kq*8);
    *(f16x8*)(hsb + (kq>>2)*1024 + (((kq&3)*16) + r)*16) = pack8(s4[0], s4[1]);
    #pragma unroll
    for (int jt = 0; jt < 2; ++jt)
      #pragma unroll
      for (int q = 0; q < 4; ++q)
        hold[jt][q] = wsh[((size_t)(dir*64 + bbase + g*4 + q))*256 + j0 + jt*16 + lr];
  }
  __syncthreads();
  // wave-parity priority: odd waves race ahead -> their gate VALU overlaps
  // even waves' MFMA issue (phase skew on each SIMD).
  if (w & 1) __builtin_amdgcn_s_setprio(1);

  const int t0 = dir ? (1023 - sbase) : sbase;
  char* optr = (char*)out16 + ((size_t)t0*64 + bbase + g*4)*1024
             + (size_t)(dir*256 + j0 + lr)*2;
  const ptrdiff_t ostep = dir ? -(ptrdiff_t)65536 : (ptrdiff_t)65536;
  const _Float16* gp = gxin + ((size_t)(dir*CT)*4 + bsl)*12288 + (size_t)tid*24;
  const ptrdiff_t gstep = 4*12288;

#define REC_STEP(RB)                                                               \
  {                                                                                \
    const f16x8 gv0 = *(const f16x8*)(gp);                                         \
    const f16x8 gv1 = *(const f16x8*)(gp + 8);                                     \
    const f16x8 gv2 = *(const f16x8*)(gp + 16);                                    \
    gp += gstep;                                                                   \
    {                                                                              \
      f32x4 ar = (f32x4){0.f,0.f,0.f,0.f};                                         \
      f32x4 az = (f32x4){0.f,0.f,0.f,0.f};                                         \
      f32x4 an = (f32x4){bn0,bn0,bn0,bn0};                                         \
      _Pragma("unroll")                                                            \
      for (int kk = 0; kk < 8; ++kk) {                                             \
        const f16x8 af = *(const f16x8*)(afp + (RB)*8192 + kk*1024);               \
        ar = MFMA(af, wf[0][kk], ar);                                              \
        az = MFMA(af, wf[2][kk], az);                                              \
        an = MFMA(af, wf[4][kk], an);                                              \
      }                                                                            \
      _Pragma("unroll")                                                            \
      for (int q = 0; q < 4; ++q) {                                                \
        const float rv = __builtin_amdgcn_rcpf(                                    \
            1.f + __builtin_amdgcn_exp2f((float)gv0[q] + ar[q]));                  \
        const float zv = __builtin_amdgcn_rcpf(                                    \
            1.f + __builtin_amdgcn_exp2f((float)gv1[q] + az[q]));                  \
        const float nv = __builtin_fmaf(-2.f, __builtin_amdgcn_rcpf(               \
            1.f + __builtin_amdgcn_exp2f(                                          \
                __builtin_fmaf(rv, an[q], (float)gv2[q]))), 1.f);                  \
        const float h = __builtin_fmaf(zv, hold[0][q] - nv, nv);                   \
        hold[0][q] = h;                                                            \
        const _Float16 hf = (_Float16)h;                                           \
        *(_Float16*)(hwp + ((RB)^1)*8192 + q*16) = hf;                             \
        *(_Float16*)(optr + q*1024) = hf;                                          \
      }                                                                            \
    }                                                                              \
    {                                                                              \
      f32x4 ar = (f32x4){0.f,0.f,0.f,0.f};                                         \
      f32x4 az = (f32x4){0.f,0.f,0.f,0.f};                                         \
      f32x4 an = (f32x4){bn1,bn1,bn1,bn1};                                         \
      _Pragma("unroll")                                                            \
      for (int kk = 0; kk < 8; ++kk) {                                             \
        const f16x8 af = *(const f16x8*)(afp + (RB)*8192 + kk*1024);               \
        ar = MFMA(af, wf[1][kk], ar);                                              \
        az = MFMA(af, wf[3][kk], az);                                              \
        an = MFMA(af, wf[5][kk], an);                                              \
      }                                                                            \
      _Pragma("unroll")                                                            \
      for (int q = 0; q < 4; ++q) {                                                \
        const float rv = __builtin_amdgcn_rcpf(                                    \
            1.f + __builtin_amdgcn_exp2f((float)gv0[4+q] + ar[q]));                \
        const float zv = __builtin_amdgcn_rcpf(                                    \
            1.f + __builtin_amdgcn_exp2f((float)gv1[4+q] + az[q]));                \
        const float nv = __builtin_fmaf(-2.f, __builtin_amdgcn_rcpf(               \
            1.f + __builtin_amdgcn_exp2f(                                          \
                __builtin_fmaf(rv, an[q], (float)gv2[4+q]))), 1.f);                \
        const float h = __builtin_fmaf(zv, hold[1][q] - nv, nv);                   \
        hold[1][q] = h;                                                            \
        const _Float16 hf = (_Float16)h;                                           \
        *(_Float16*)(hwp + ((RB)^1)*8192 + 512 + q*16) = hf;                       \
        *(_Float16*)(optr + q*1024 + 32) = hf;                                     \
      }                                                                            \
    }                                                                              \
    optr += ostep;                                                                 \
    asm volatile("s_waitcnt lgkmcnt(0)" ::: "memory");                             \
    __builtin_amdgcn_s_barrier();                                                  \
    asm volatile("" ::: "memory");                                                 \
  }

  #pragma unroll 1
  for (int sc = 0; sc < CT; sc += 2) {
    REC_STEP(0)
    REC_STEP(1)
  }
#undef REC_STEP

  if (sbase + CT == 1024) {                  // final h -> hidden output
    #pragma unroll
    for (int jt = 0; jt < 2; ++jt)
      #pragma unroll
      for (int q = 0; q < 4; ++q)
        hidden[((size_t)(dir*64 + bbase + g*4 + q))*256 + j0 + jt*16 + lr] = hold[jt][q];
  } else {                                   // persist h for next chunk
    #pragma unroll
    for (int jt = 0; jt < 2; ++jt)
      #pragma unroll
      for (int q = 0; q < 4; ++q)
        wsh[((size_t)(dir*64 + bbase + g*4 + q))*256 + j0 + jt*16 + lr] = hold[jt][q];
  }
}

// ---------------- FC in place: relu(concat_f16 @ W_fc^T + b) -> f32 ----------------
__global__ __launch_bounds__(256) void k_fc(
    const _Float16* __restrict__ h16, const float* __restrict__ Wfc,
    const float* __restrict__ bfc, float* __restrict__ out)
{
  const int mt = blockIdx.x;
  __shared__ _Float16 As[64*512];            // 64KB
  const int tid = threadIdx.x, w = tid >> 6, l = tid & 63;
  const int lr = l & 15, g = l >> 4;
  #pragma unroll
  for (int i = 0; i < 16; ++i) {
    int c = tid + i*256, r = c >> 6, cc = c & 63;
    *(int4*)((char*)As + SWZ2(r, cc*16)) =
        *(const int4*)((const char*)h16 + ((size_t)mt*64 + r)*1024 + cc*16);
  }
  __syncthreads();                           // all h16 reads drained before any store
  #pragma unroll 1
  for (int nt = 0; nt < 4; ++nt) {
    f32x4 acc[4];
    #pragma unroll
    for (int ct = 0; ct < 4; ++ct) acc[ct] = (f32x4){0.f,0.f,0.f,0.f};
    #pragma unroll 2
    for (int kk = 0; kk < 16; ++kk) {
      f16x8 af = *(const f16x8*)((const char*)As + SWZ2(w*16 + lr, kk*64 + g*16));
      #pragma unroll
      for (int ct = 0; ct < 4; ++ct) {
        const float4* s4 = (const float4*)(Wfc + (size_t)(nt*64 + ct*16 + lr)*512 + kk*32 + g*8);
        acc[ct] = MFMA(af, pack8(s4[0], s4[1]), acc[ct]);
      }
    }
    #pragma unroll
    for (int ct = 0; ct < 4; ++ct) {
      const int col = nt*64 + ct*16 + lr;
      const float bv = bfc[col];
      #pragma unroll
      for (int q = 0; q < 4; ++q) {
        const int row = w*16 + g*4 + q;
        out[((size_t)mt*64 + row)*256 + col] = fmaxf(acc[ct][q] + bv, 0.f);
      }
    }
  }
}

extern "C" void kernel_launch(void* const* d_in, const int* in_sizes, int n_in,
                              void* d_out, int out_size, void* d_ws, size_t ws_size,
                              hipStream_t stream) {
  const float* X      = (const float*)d_in[0];
  const float* W_ih_f = (const float*)d_in[1];
  const float* W_hh_f = (const float*)d_in[2];
  const float* b_ih_f = (const float*)d_in[3];
  const float* b_hh_f = (const float*)d_in[4];
  const float* W_ih_b = (const float*)d_in[5];
  const float* W_hh_b = (const float*)d_in[6];
  const float* b_ih_b = (const float*)d_in[7];
  const float* b_hh_b = (const float*)d_in[8];
  const float* W_fc   = (const float*)d_in[9];
  const float* b_fc   = (const float*)d_in[10];

  // gxc DOUBLE-buffered (rec reads one while gx blocks fill the other).
  // ws need = 2*CT*196608 + 131072; CT=256 -> 100.8MB (round-3: ws >= 201.5MB).
  int CT = 256;
  while (CT > 8 && (2*(size_t)CT*196608 + 131072) > ws_size) CT >>= 1;
  const size_t CTB = (size_t)CT*196608;
  _Float16* buf0 = (_Float16*)d_ws;
  _Float16* buf1 = (_Float16*)((char*)d_ws + CTB);
  float*    wsh  = (float*)((char*)d_ws + 2*CTB);      // [2][64][256] f32

  _Float16* h16   = (_Float16*)d_out;                  // [1024][64][512] f16 (in-place)
  float*    out   = (float*)d_out;                     // [1024][64][256] f32
  float*    hidden= (float*)d_out + (size_t)1024*64*256;

  const int NC = 1024 / CT;
  k_gx0<<<dim3(CT, 2), dim3(512), 0, stream>>>(X, W_ih_f, b_ih_f, b_hh_f,
                                               W_ih_b, b_ih_b, b_hh_b, buf0, CT, 0);
  for (int c = 0; c < NC; ++c) {
    _Float16* bin  = (c & 1) ? buf1 : buf0;
    _Float16* bout = (c & 1) ? buf0 : buf1;
    k_step<<<dim3(8 + 2*CT), dim3(512), 0, stream>>>(
        W_hh_f, b_hh_f, W_hh_b, b_hh_b, bin, wsh, h16, hidden, CT, c*CT,
        X, W_ih_f, b_ih_f, b_hh_f, W_ih_b, b_ih_b, b_hh_b,
        bout, (c+1)*CT, (c < NC-1) ? 1 : 0);
  }
  k_fc<<<dim3(1024), dim3(256), 0, stream>>>(h16, W_fc, b_fc, out);
}